// Round 1
// baseline (17821.057 us; speedup 1.0000x reference)
//
#include <hip/hip_runtime.h>
#include <math.h>

constexpr int B = 2;
constexpr int F = 2112;
constexpr int D = 1024;
constexpr int H = 8;
constexpr int DH = 64;
constexpr int INNER = H * DH;      // 512
constexpr int NL = 721;
constexpr int VD = 64;
constexpr int DEPTH = 6;
constexpr int FN = F + NL;         // 2833
constexpr float EPS = 1e-5f;

// ---------------- block reduce (sum, sumsq) over 256 threads ----------------
__device__ __forceinline__ void block_reduce_2(float& s, float& ss, float* red)
{
#pragma unroll
    for (int off = 32; off; off >>= 1) {
        s  += __shfl_xor(s, off);
        ss += __shfl_xor(ss, off);
    }
    int wv = threadIdx.x >> 6;
    if ((threadIdx.x & 63) == 0) { red[wv] = s; red[4 + wv] = ss; }
    __syncthreads();
    s  = red[0] + red[1] + red[2] + red[3];
    ss = red[4] + red[5] + red[6] + red[7];
}

// ------------- x + spatial_emb + frame_emb, then row-normalize --------------
// one block per row (B*F rows), 256 threads, D=1024 -> float4 per thread
__global__ __launch_bounds__(256) void emb_ln_kernel(
    const float* __restrict__ x, const float* __restrict__ sp_emb,
    const float* __restrict__ fr_emb, float* __restrict__ xhat)
{
    __shared__ float red[8];
    int r = blockIdx.x;            // r = b*F + j
    int j = r % F;
    int t = threadIdx.x;
    const float4* xr = (const float4*)(x + (long)r * D);
    int spr = (j < VD) ? j : VD;
    int frr = (j < VD) ? 0 : (j - VD + 1);
    const float4* sp4 = (const float4*)(sp_emb + (long)spr * D);
    const float4* fr4 = (const float4*)(fr_emb + (long)frr * D);
    float4 v = xr[t], a = sp4[t], c = fr4[t];
    v.x += a.x + c.x; v.y += a.y + c.y; v.z += a.z + c.z; v.w += a.w + c.w;
    float s  = v.x + v.y + v.z + v.w;
    float ss = v.x*v.x + v.y*v.y + v.z*v.z + v.w*v.w;
    block_reduce_2(s, ss, red);
    float mean = s * (1.0f / D);
    float var  = ss * (1.0f / D) - mean * mean;
    float rstd = rsqrtf(var + EPS);
    float4 o;
    o.x = (v.x - mean) * rstd; o.y = (v.y - mean) * rstd;
    o.z = (v.z - mean) * rstd; o.w = (v.w - mean) * rstd;
    ((float4*)(xhat + (long)r * D))[t] = o;
}

// --------------------------- plain row-normalize ----------------------------
__global__ __launch_bounds__(256) void rownorm_kernel(
    const float* __restrict__ in, float* __restrict__ out)
{
    __shared__ float red[8];
    int r = blockIdx.x;
    int t = threadIdx.x;
    float4 v = ((const float4*)(in + (long)r * D))[t];
    float s  = v.x + v.y + v.z + v.w;
    float ss = v.x*v.x + v.y*v.y + v.z*v.z + v.w*v.w;
    block_reduce_2(s, ss, red);
    float mean = s * (1.0f / D);
    float var  = ss * (1.0f / D) - mean * mean;
    float rstd = rsqrtf(var + EPS);
    float4 o;
    o.x = (v.x - mean) * rstd; o.y = (v.y - mean) * rstd;
    o.z = (v.z - mean) * rstd; o.w = (v.w - mean) * rstd;
    ((float4*)(out + (long)r * D))[t] = o;
}

// ------------------------ final LN with affine -> out ------------------------
__global__ __launch_bounds__(256) void final_ln_kernel(
    const float* __restrict__ in, const float* __restrict__ g,
    const float* __restrict__ b, float* __restrict__ out)
{
    __shared__ float red[8];
    int r = blockIdx.x;
    int t = threadIdx.x;
    float4 v = ((const float4*)(in + (long)r * D))[t];
    float s  = v.x + v.y + v.z + v.w;
    float ss = v.x*v.x + v.y*v.y + v.z*v.z + v.w*v.w;
    block_reduce_2(s, ss, red);
    float mean = s * (1.0f / D);
    float var  = ss * (1.0f / D) - mean * mean;
    float rstd = rsqrtf(var + EPS);
    float4 g4 = ((const float4*)g)[t];
    float4 b4 = ((const float4*)b)[t];
    float4 o;
    o.x = (v.x - mean) * rstd * g4.x + b4.x;
    o.y = (v.y - mean) * rstd * g4.y + b4.y;
    o.z = (v.z - mean) * rstd * g4.z + b4.z;
    o.w = (v.w - mean) * rstd * g4.w + b4.w;
    ((float4*)(out + (long)r * D))[t] = o;
}

// ---------------------- lat init: broadcast latents to B ---------------------
__global__ __launch_bounds__(256) void lat_init_kernel(
    const float* __restrict__ latents, float* __restrict__ lat)
{
    int r = blockIdx.x;            // b*NL + i
    int i = r % NL;
    int t = threadIdx.x;
    ((float4*)(lat + (long)r * D))[t] = ((const float4*)(latents + (long)i * D))[t];
}

// ------------------------------ generic GEMM --------------------------------
// C[row_map(r), n] = epilogue( scale * sum_k (A[r,k]*g[k]+b[k]) * W[k,n] )
// row_map: batch = r / rpb ; out_row = roff + r % rpb ; ptr = C + batch*cbs + out_row*ldc
// mode: 0 = store, 1 = gelu-store, 2 = residual add (C += val)
#define MODE_STORE 0
#define MODE_GELU  1
#define MODE_RES   2

__global__ __launch_bounds__(256) void gemm_kernel(
    const float* __restrict__ A, const float* __restrict__ W,
    float* __restrict__ C,
    const float* __restrict__ gvec, const float* __restrict__ bvec,
    int M, int N, int K,
    int rpb, long long cbs, int roff, int ldc,
    float scale, int mode)
{
    __shared__ float As[16][64];
    __shared__ float Bs[16][64];
    int tid = threadIdx.x;
    int m0 = blockIdx.x * 64;
    int n0 = blockIdx.y * 64;
    int mr = tid & 15;             // micro-row group
    int mc = tid >> 4;             // micro-col group

    // A staging indices: each thread loads one float4 of A (16 rows x 64... -> 64 rows x 16 k)
    int arow = m0 + (tid >> 2);
    int ak   = (tid & 3) * 4;
    bool avalid = arow < M;
    const float* Aptr = A + (long)arow * K + ak;
    // B staging: row k0 + (tid>>4), cols n0 + (tid&15)*4
    const float* Wptr = W + (long)(tid >> 4) * N + n0 + (tid & 15) * 4;

    float acc[4][4] = {};

    for (int k0 = 0; k0 < K; k0 += 16) {
        float4 a;
        if (avalid) a = *(const float4*)(Aptr + k0);
        else        { a.x = a.y = a.z = a.w = 0.0f; }
        if (gvec) {
            int kk = k0 + ak;
            a.x = a.x * gvec[kk + 0] + bvec[kk + 0];
            a.y = a.y * gvec[kk + 1] + bvec[kk + 1];
            a.z = a.z * gvec[kk + 2] + bvec[kk + 2];
            a.w = a.w * gvec[kk + 3] + bvec[kk + 3];
        }
        float4 w4 = *(const float4*)(Wptr + (long)k0 * N);
        __syncthreads();
        As[ak + 0][tid >> 2] = a.x;
        As[ak + 1][tid >> 2] = a.y;
        As[ak + 2][tid >> 2] = a.z;
        As[ak + 3][tid >> 2] = a.w;
        *(float4*)&Bs[tid >> 4][(tid & 15) * 4] = w4;
        __syncthreads();
#pragma unroll
        for (int k = 0; k < 16; ++k) {
            float4 av = *(const float4*)&As[k][mr * 4];
            float4 bv = *(const float4*)&Bs[k][mc * 4];
            acc[0][0] += av.x * bv.x; acc[0][1] += av.x * bv.y; acc[0][2] += av.x * bv.z; acc[0][3] += av.x * bv.w;
            acc[1][0] += av.y * bv.x; acc[1][1] += av.y * bv.y; acc[1][2] += av.y * bv.z; acc[1][3] += av.y * bv.w;
            acc[2][0] += av.z * bv.x; acc[2][1] += av.z * bv.y; acc[2][2] += av.z * bv.z; acc[2][3] += av.z * bv.w;
            acc[3][0] += av.w * bv.x; acc[3][1] += av.w * bv.y; acc[3][2] += av.w * bv.z; acc[3][3] += av.w * bv.w;
        }
    }

#pragma unroll
    for (int i = 0; i < 4; ++i) {
        int ar = m0 + mr * 4 + i;
        if (ar >= M) continue;
        int bb = ar / rpb;
        int jr = ar % rpb;
        float* crow = C + (long long)bb * cbs + (long)(roff + jr) * ldc + n0 + mc * 4;
#pragma unroll
        for (int j = 0; j < 4; ++j) {
            float val = acc[i][j] * scale;
            if (mode == MODE_GELU) {
                val = 0.5f * val * (1.0f + erff(val * 0.70710678118654752f));
            } else if (mode == MODE_RES) {
                val = crow[j] + val;
            }
            crow[j] = val;
        }
    }
}

// ----------------------- fused attention (online softmax) -------------------
// one wave per (b, h, i); lane d owns head-dim d.
__global__ __launch_bounds__(256) void attn_kernel(
    const float* __restrict__ q, const float* __restrict__ kv,
    const int* __restrict__ split, float* __restrict__ o)
{
    int wid = blockIdx.x * 4 + (threadIdx.x >> 6);
    if (wid >= B * H * NL) return;
    int lane = threadIdx.x & 63;
    int b = wid / (H * NL);
    int rem = wid % (H * NL);
    int h = rem / NL;
    int i = rem % NL;

    int kcol = h * DH + lane;
    const float qd = q[((long)b * NL + i) * INNER + kcol];
    const float* kvb = kv + (long)b * FN * (2 * INNER);
    int sp = split[b];
    if (sp < 0) sp = 0;
    if (sp > F) sp = F;

    float m = -INFINITY, l = 0.0f, acc = 0.0f;

    for (int j = 0; j < sp; ++j) {
        const float* row = kvb + (long)j * (2 * INNER);
        float s = qd * row[kcol];
#pragma unroll
        for (int off = 32; off; off >>= 1) s += __shfl_xor(s, off);
        float mn = fmaxf(m, s);
        float p  = __expf(s - mn);
        float cr = __expf(m - mn);
        l   = l * cr + p;
        acc = acc * cr + p * row[INNER + kcol];
        m = mn;
    }
    for (int j = F; j < FN; ++j) {
        const float* row = kvb + (long)j * (2 * INNER);
        float s = qd * row[kcol];
#pragma unroll
        for (int off = 32; off; off >>= 1) s += __shfl_xor(s, off);
        float mn = fmaxf(m, s);
        float p  = __expf(s - mn);
        float cr = __expf(m - mn);
        l   = l * cr + p;
        acc = acc * cr + p * row[INNER + kcol];
        m = mn;
    }
    o[((long)b * NL + i) * INNER + kcol] = acc / l;
}

// ------------------------------- host side ----------------------------------
static void launch_gemm(const float* A, const float* W, float* C,
                        const float* g, const float* bv,
                        int M, int N, int K,
                        int rpb, long long cbs, int roff, int ldc,
                        float scale, int mode, hipStream_t s)
{
    dim3 grid((M + 63) / 64, N / 64);
    gemm_kernel<<<grid, 256, 0, s>>>(A, W, C, g, bv, M, N, K, rpb, cbs, roff, ldc, scale, mode);
}

extern "C" void kernel_launch(void* const* d_in, const int* in_sizes, int n_in,
                              void* d_out, int out_size, void* d_ws, size_t ws_size,
                              hipStream_t stream)
{
    const float* x        = (const float*)d_in[0];
    const int*   split    = (const int*)d_in[1];
    const float* latents  = (const float*)d_in[2];
    const float* sp_emb   = (const float*)d_in[3];
    const float* fr_emb   = (const float*)d_in[4];
    const float* nm_g     = (const float*)d_in[5];
    const float* nm_b     = (const float*)d_in[6];
    const float* nl_g     = (const float*)d_in[7];
    const float* nl_b     = (const float*)d_in[8];
    const float* wq       = (const float*)d_in[9];
    const float* wkv      = (const float*)d_in[10];
    const float* wo       = (const float*)d_in[11];
    const float* ffn_g    = (const float*)d_in[12];
    const float* ffn_b    = (const float*)d_in[13];
    const float* ffw1     = (const float*)d_in[14];
    const float* ffw2     = (const float*)d_in[15];
    const float* final_g  = (const float*)d_in[16];
    const float* final_b  = (const float*)d_in[17];
    float* out = (float*)d_out;

    // workspace layout (floats)
    float* ws = (float*)d_ws;
    const long XH = (long)B * F * D;          // 4,325,376
    const long LT = (long)B * NL * D;         // 1,476,608
    const long QS = (long)B * NL * INNER;     //   738,304
    const long KV = (long)B * FN * 2 * INNER; // 5,801,984
    const long H1 = (long)B * NL * 4 * D;     // 5,906,432
    float* xhat = ws;
    float* lat  = xhat + XH;
    float* latn = lat + LT;
    float* qb   = latn + LT;
    float* kvb  = qb + QS;
    float* ob   = kvb + KV;
    float* h1   = ob + QS;

    // 1) embeddings + LN-normalize of x (reused across all 6 layers)
    emb_ln_kernel<<<B * F, 256, 0, stream>>>(x, sp_emb, fr_emb, xhat);
    // 2) lat init
    lat_init_kernel<<<B * NL, 256, 0, stream>>>(latents, lat);

    const int MLAT = B * NL;   // 1442
    const int MX   = B * F;    // 4224

    for (int l = 0; l < DEPTH; ++l) {
        const float* wq_l   = wq   + (long)l * D * INNER;
        const float* wkv_l  = wkv  + (long)l * D * 2 * INNER;
        const float* wo_l   = wo   + (long)l * INNER * D;
        const float* ffw1_l = ffw1 + (long)l * D * 4 * D;
        const float* ffw2_l = ffw2 + (long)l * 4 * D * D;

        // latn = rownorm(lat)
        rownorm_kernel<<<MLAT, 256, 0, stream>>>(lat, latn);

        // q = (latn*nl_g+nl_b) @ wq * scale
        launch_gemm(latn, wq_l, qb, nl_g + l * D, nl_b + l * D,
                    MLAT, INNER, D, MLAT, 0, 0, INNER, 0.125f, MODE_STORE, stream);

        // kv (x part): rows j in [0,F) of each batch
        launch_gemm(xhat, wkv_l, kvb, nm_g + l * D, nm_b + l * D,
                    MX, 2 * INNER, D, F, (long long)FN * 2 * INNER, 0, 2 * INNER,
                    1.0f, MODE_STORE, stream);
        // kv (latent part): rows j in [F, FN)
        launch_gemm(latn, wkv_l, kvb, nl_g + l * D, nl_b + l * D,
                    MLAT, 2 * INNER, D, NL, (long long)FN * 2 * INNER, F, 2 * INNER,
                    1.0f, MODE_STORE, stream);

        // fused attention
        attn_kernel<<<(B * H * NL + 3) / 4, 256, 0, stream>>>(qb, kvb, split, ob);

        // lat += o @ wo
        launch_gemm(ob, wo_l, lat, nullptr, nullptr,
                    MLAT, D, INNER, MLAT, 0, 0, D, 1.0f, MODE_RES, stream);

        // FFN
        rownorm_kernel<<<MLAT, 256, 0, stream>>>(lat, latn);
        launch_gemm(latn, ffw1_l, h1, ffn_g + l * D, ffn_b + l * D,
                    MLAT, 4 * D, D, MLAT, 0, 0, 4 * D, 1.0f, MODE_GELU, stream);
        launch_gemm(h1, ffw2_l, lat, nullptr, nullptr,
                    MLAT, D, 4 * D, MLAT, 0, 0, D, 1.0f, MODE_RES, stream);
    }

    // final LN -> out
    final_ln_kernel<<<MLAT, 256, 0, stream>>>(lat, final_g, final_b, out);
}

// Round 2
// 5790.767 us; speedup vs baseline: 3.0775x; 3.0775x over previous
//
#include <hip/hip_runtime.h>
#include <math.h>

constexpr int B = 2;
constexpr int F = 2112;
constexpr int D = 1024;
constexpr int H = 8;
constexpr int DH = 64;
constexpr int INNER = H * DH;      // 512
constexpr int NL = 721;
constexpr int NL_PAD = 768;
constexpr int VD = 64;
constexpr int DEPTH = 6;
constexpr int FN = F + NL;         // 2833
constexpr int FN_PAD = 2880;       // 45 * 64
constexpr float EPS = 1e-5f;

typedef __bf16 bf16x8 __attribute__((ext_vector_type(8)));
typedef float  f32x4  __attribute__((ext_vector_type(4)));

static __device__ __forceinline__ unsigned short f2bf(float f)
{
    union { float f; unsigned int u; } x; x.f = f;
    unsigned int r = x.u + 0x7FFFu + ((x.u >> 16) & 1u);   // RNE
    return (unsigned short)(r >> 16);
}

// ---------------- block reduce (sum, sumsq) over 256 threads ----------------
__device__ __forceinline__ void block_reduce_2(float& s, float& ss, float* red)
{
#pragma unroll
    for (int off = 32; off; off >>= 1) {
        s  += __shfl_xor(s, off);
        ss += __shfl_xor(ss, off);
    }
    int wv = threadIdx.x >> 6;
    if ((threadIdx.x & 63) == 0) { red[wv] = s; red[4 + wv] = ss; }
    __syncthreads();
    s  = red[0] + red[1] + red[2] + red[3];
    ss = red[4] + red[5] + red[6] + red[7];
}

// ------------- x + spatial_emb + frame_emb, then row-normalize --------------
__global__ __launch_bounds__(256) void emb_ln_kernel(
    const float* __restrict__ x, const float* __restrict__ sp_emb,
    const float* __restrict__ fr_emb, float* __restrict__ xhat)
{
    __shared__ float red[8];
    int r = blockIdx.x;            // r = b*F + j
    int j = r % F;
    int t = threadIdx.x;
    const float4* xr = (const float4*)(x + (long)r * D);
    int spr = (j < VD) ? j : VD;
    int frr = (j < VD) ? 0 : (j - VD + 1);
    const float4* sp4 = (const float4*)(sp_emb + (long)spr * D);
    const float4* fr4 = (const float4*)(fr_emb + (long)frr * D);
    float4 v = xr[t], a = sp4[t], c = fr4[t];
    v.x += a.x + c.x; v.y += a.y + c.y; v.z += a.z + c.z; v.w += a.w + c.w;
    float s  = v.x + v.y + v.z + v.w;
    float ss = v.x*v.x + v.y*v.y + v.z*v.z + v.w*v.w;
    block_reduce_2(s, ss, red);
    float mean = s * (1.0f / D);
    float var  = ss * (1.0f / D) - mean * mean;
    float rstd = rsqrtf(var + EPS);
    float4 o;
    o.x = (v.x - mean) * rstd; o.y = (v.y - mean) * rstd;
    o.z = (v.z - mean) * rstd; o.w = (v.w - mean) * rstd;
    ((float4*)(xhat + (long)r * D))[t] = o;
}

// --------------------------- plain row-normalize ----------------------------
__global__ __launch_bounds__(256) void rownorm_kernel(
    const float* __restrict__ in, float* __restrict__ out)
{
    __shared__ float red[8];
    int r = blockIdx.x;
    int t = threadIdx.x;
    float4 v = ((const float4*)(in + (long)r * D))[t];
    float s  = v.x + v.y + v.z + v.w;
    float ss = v.x*v.x + v.y*v.y + v.z*v.z + v.w*v.w;
    block_reduce_2(s, ss, red);
    float mean = s * (1.0f / D);
    float var  = ss * (1.0f / D) - mean * mean;
    float rstd = rsqrtf(var + EPS);
    float4 o;
    o.x = (v.x - mean) * rstd; o.y = (v.y - mean) * rstd;
    o.z = (v.z - mean) * rstd; o.w = (v.w - mean) * rstd;
    ((float4*)(out + (long)r * D))[t] = o;
}

// ------------------------ final LN with affine -> out ------------------------
__global__ __launch_bounds__(256) void final_ln_kernel(
    const float* __restrict__ in, const float* __restrict__ g,
    const float* __restrict__ b, float* __restrict__ out)
{
    __shared__ float red[8];
    int r = blockIdx.x;
    int t = threadIdx.x;
    float4 v = ((const float4*)(in + (long)r * D))[t];
    float s  = v.x + v.y + v.z + v.w;
    float ss = v.x*v.x + v.y*v.y + v.z*v.z + v.w*v.w;
    block_reduce_2(s, ss, red);
    float mean = s * (1.0f / D);
    float var  = ss * (1.0f / D) - mean * mean;
    float rstd = rsqrtf(var + EPS);
    float4 g4 = ((const float4*)g)[t];
    float4 b4 = ((const float4*)b)[t];
    float4 o;
    o.x = (v.x - mean) * rstd * g4.x + b4.x;
    o.y = (v.y - mean) * rstd * g4.y + b4.y;
    o.z = (v.z - mean) * rstd * g4.z + b4.z;
    o.w = (v.w - mean) * rstd * g4.w + b4.w;
    ((float4*)(out + (long)r * D))[t] = o;
}

// ---------------------- lat init: broadcast latents to B ---------------------
__global__ __launch_bounds__(256) void lat_init_kernel(
    const float* __restrict__ latents, float* __restrict__ lat)
{
    int r = blockIdx.x;            // b*NL + i
    int i = r % NL;
    int t = threadIdx.x;
    ((float4*)(lat + (long)r * D))[t] = ((const float4*)(latents + (long)i * D))[t];
}

// ------------------------------ generic GEMM --------------------------------
// modes:
#define MODE_STORE 0   // fp32 store
#define MODE_GELU  1   // fp32 gelu store
#define MODE_RES   2   // fp32 residual add
#define MODE_BF16  3   // bf16 store (C = ushort*)
#define MODE_KV    4   // cols<INNER -> K bf16 into C; cols>=INNER -> Vt bf16 into C2

__global__ __launch_bounds__(256) void gemm_kernel(
    const float* __restrict__ A, const float* __restrict__ W,
    float* __restrict__ C, float* __restrict__ C2,
    const float* __restrict__ gvec, const float* __restrict__ bvec,
    int M, int N, int K,
    int rpb, long long cbs, int roff, int ldc,
    float scale, int mode)
{
    __shared__ float As[16][64];
    __shared__ float Bs[16][64];
    int tid = threadIdx.x;
    int m0 = blockIdx.x * 64;
    int n0 = blockIdx.y * 64;
    int mr = tid & 15;
    int mc = tid >> 4;

    int arow = m0 + (tid >> 2);
    int ak   = (tid & 3) * 4;
    bool avalid = arow < M;
    const float* Aptr = A + (long)arow * K + ak;
    const float* Wptr = W + (long)(tid >> 4) * N + n0 + (tid & 15) * 4;

    float acc[4][4] = {};

    for (int k0 = 0; k0 < K; k0 += 16) {
        float4 a;
        if (avalid) a = *(const float4*)(Aptr + k0);
        else        { a.x = a.y = a.z = a.w = 0.0f; }
        if (gvec) {
            int kk = k0 + ak;
            a.x = a.x * gvec[kk + 0] + bvec[kk + 0];
            a.y = a.y * gvec[kk + 1] + bvec[kk + 1];
            a.z = a.z * gvec[kk + 2] + bvec[kk + 2];
            a.w = a.w * gvec[kk + 3] + bvec[kk + 3];
        }
        float4 w4 = *(const float4*)(Wptr + (long)k0 * N);
        __syncthreads();
        As[ak + 0][tid >> 2] = a.x;
        As[ak + 1][tid >> 2] = a.y;
        As[ak + 2][tid >> 2] = a.z;
        As[ak + 3][tid >> 2] = a.w;
        *(float4*)&Bs[tid >> 4][(tid & 15) * 4] = w4;
        __syncthreads();
#pragma unroll
        for (int k = 0; k < 16; ++k) {
            float4 av = *(const float4*)&As[k][mr * 4];
            float4 bv = *(const float4*)&Bs[k][mc * 4];
            acc[0][0] += av.x * bv.x; acc[0][1] += av.x * bv.y; acc[0][2] += av.x * bv.z; acc[0][3] += av.x * bv.w;
            acc[1][0] += av.y * bv.x; acc[1][1] += av.y * bv.y; acc[1][2] += av.y * bv.z; acc[1][3] += av.y * bv.w;
            acc[2][0] += av.z * bv.x; acc[2][1] += av.z * bv.y; acc[2][2] += av.z * bv.z; acc[2][3] += av.z * bv.w;
            acc[3][0] += av.w * bv.x; acc[3][1] += av.w * bv.y; acc[3][2] += av.w * bv.z; acc[3][3] += av.w * bv.w;
        }
    }

#pragma unroll
    for (int i = 0; i < 4; ++i) {
        int ar = m0 + mr * 4 + i;
        if (ar >= M) continue;
        int bb = ar / rpb;
        int jr = ar % rpb;
        int j  = roff + jr;
        if (mode == MODE_KV) {
            int n = n0 + mc * 4;
            unsigned short u0 = f2bf(acc[i][0]), u1 = f2bf(acc[i][1]);
            unsigned short u2 = f2bf(acc[i][2]), u3 = f2bf(acc[i][3]);
            if (n < INNER) {
                ushort4 pk; pk.x = u0; pk.y = u1; pk.z = u2; pk.w = u3;
                *(ushort4*)((unsigned short*)C + ((long)bb * FN_PAD + j) * INNER + n) = pk;
            } else {
                unsigned short* vtp = (unsigned short*)C2;
                int nn = n - INNER;
                vtp[((long)bb * H * DH + nn + 0) * FN_PAD + j] = u0;
                vtp[((long)bb * H * DH + nn + 1) * FN_PAD + j] = u1;
                vtp[((long)bb * H * DH + nn + 2) * FN_PAD + j] = u2;
                vtp[((long)bb * H * DH + nn + 3) * FN_PAD + j] = u3;
            }
        } else if (mode == MODE_BF16) {
            ushort4 pk;
            pk.x = f2bf(acc[i][0] * scale); pk.y = f2bf(acc[i][1] * scale);
            pk.z = f2bf(acc[i][2] * scale); pk.w = f2bf(acc[i][3] * scale);
            *(ushort4*)((unsigned short*)C + (long)bb * cbs + (long)j * ldc + n0 + mc * 4) = pk;
        } else {
            float* crow = C + (long long)bb * cbs + (long)j * ldc + n0 + mc * 4;
#pragma unroll
            for (int jc = 0; jc < 4; ++jc) {
                float val = acc[i][jc] * scale;
                if (mode == MODE_GELU) {
                    val = 0.5f * val * (1.0f + erff(val * 0.70710678118654752f));
                } else if (mode == MODE_RES) {
                    val = crow[jc] + val;
                }
                crow[jc] = val;
            }
        }
    }
}

// ----------------------- MFMA flash attention --------------------------------
// grid: (ceil(NL/64)=12, B*H). 4 waves/block, each wave owns 16 q-rows.
// KV tiles of 64 keys; K row-major [b][key][INNER] bf16, V transposed
// [b][h][d][key] bf16. Online softmax per q-row.
__global__ __launch_bounds__(256) void attn_mfma_kernel(
    const unsigned short* __restrict__ qb, const unsigned short* __restrict__ kb,
    const unsigned short* __restrict__ vt, const int* __restrict__ split,
    float* __restrict__ o)
{
    int bh = blockIdx.y;
    int b  = bh >> 3;
    int h  = bh & 7;
    int w  = threadIdx.x >> 6;
    int lane = threadIdx.x & 63;
    int q0 = blockIdx.x * 64 + w * 16;
    if (q0 >= NL) return;

    __shared__ unsigned short p_lds[4][16 * 64];   // 2KB per wave, XOR-swizzled
    unsigned short* pl = p_lds[w];

    int lr = lane & 15;        // frag row/col lane
    int lg = lane >> 4;        // k-group

    // Q A-fragments (held for the whole KV loop)
    bf16x8 qa0, qa1;
    {
        const unsigned short* qrow = qb + ((long)b * NL_PAD + q0 + lr) * INNER + h * 64;
        qa0 = *(const bf16x8*)(qrow + lg * 8);
        qa1 = *(const bf16x8*)(qrow + 32 + lg * 8);
    }

    f32x4 oacc[4] = {{0,0,0,0},{0,0,0,0},{0,0,0,0},{0,0,0,0}};
    float m[4]    = {-1e30f, -1e30f, -1e30f, -1e30f};
    float lsum[4] = {0.f, 0.f, 0.f, 0.f};

    int sp = split[b];
    if (sp < 0) sp = 0;
    if (sp > F) sp = F;
    int ntx = (sp + 63) >> 6;
    int ntot = ntx + 12;       // 12 latent tiles cover F..F+768 (masked at FN)

    for (int t = 0; t < ntot; ++t) {
        int j0, limit;
        if (t < ntx) { j0 = t * 64;            limit = sp; }
        else         { j0 = F + (t - ntx) * 64; limit = FN; }

        // ---- S = Q K^T (16 q-rows x 64 keys) ----
        f32x4 s[4] = {{0,0,0,0},{0,0,0,0},{0,0,0,0},{0,0,0,0}};
        const unsigned short* kbase =
            kb + ((long)b * FN_PAD + j0 + lr) * INNER + h * 64 + lg * 8;
#pragma unroll
        for (int st = 0; st < 4; ++st) {
            bf16x8 kf0 = *(const bf16x8*)(kbase + (long)st * 16 * INNER);
            bf16x8 kf1 = *(const bf16x8*)(kbase + (long)st * 16 * INNER + 32);
            s[st] = __builtin_amdgcn_mfma_f32_16x16x32_bf16(qa0, kf0, s[st], 0, 0, 0);
            s[st] = __builtin_amdgcn_mfma_f32_16x16x32_bf16(qa1, kf1, s[st], 0, 0, 0);
        }

        // ---- mask (boundary tiles only) ----
        if (j0 + 64 > limit) {
#pragma unroll
            for (int st = 0; st < 4; ++st) {
                bool valid = (j0 + st * 16 + lr) < limit;
#pragma unroll
                for (int r = 0; r < 4; ++r)
                    s[st][r] = valid ? s[st][r] : -1e30f;
            }
        }

        // ---- online softmax ----
        float tm[4];
#pragma unroll
        for (int r = 0; r < 4; ++r)
            tm[r] = fmaxf(fmaxf(s[0][r], s[1][r]), fmaxf(s[2][r], s[3][r]));
#pragma unroll
        for (int off = 1; off < 16; off <<= 1) {
#pragma unroll
            for (int r = 0; r < 4; ++r)
                tm[r] = fmaxf(tm[r], __shfl_xor(tm[r], off));
        }
        float cr[4];
#pragma unroll
        for (int r = 0; r < 4; ++r) {
            float mn = fmaxf(m[r], tm[r]);
            cr[r] = __expf(m[r] - mn);
            m[r]  = mn;
        }
#pragma unroll
        for (int st = 0; st < 4; ++st)
#pragma unroll
            for (int r = 0; r < 4; ++r)
                s[st][r] = __expf(s[st][r] - m[r]);
        float ts[4];
#pragma unroll
        for (int r = 0; r < 4; ++r)
            ts[r] = (s[0][r] + s[1][r]) + (s[2][r] + s[3][r]);
#pragma unroll
        for (int off = 1; off < 16; off <<= 1) {
#pragma unroll
            for (int r = 0; r < 4; ++r)
                ts[r] += __shfl_xor(ts[r], off);
        }
#pragma unroll
        for (int r = 0; r < 4; ++r)
            lsum[r] = lsum[r] * cr[r] + ts[r];
#pragma unroll
        for (int nst = 0; nst < 4; ++nst)
#pragma unroll
            for (int r = 0; r < 4; ++r)
                oacc[nst][r] *= cr[r];

        // ---- P -> LDS (bf16, XOR-swizzled rows) ----
#pragma unroll
        for (int st = 0; st < 4; ++st)
#pragma unroll
            for (int r = 0; r < 4; ++r) {
                int row  = lg * 4 + r;
                int col  = st * 16 + lr;
                int byte = (row * 128 + col * 2) ^ ((row & 7) << 4);
                *(unsigned short*)((char*)pl + byte) = f2bf(s[st][r]);
            }

        // ---- O += P V ----
#pragma unroll
        for (int kk = 0; kk < 2; ++kk) {
            int row  = lr;
            int byte = (row * 128 + kk * 64 + lg * 16) ^ ((row & 7) << 4);
            bf16x8 pa = *(const bf16x8*)((char*)pl + byte);
#pragma unroll
            for (int nst = 0; nst < 4; ++nst) {
                const unsigned short* vp =
                    vt + ((long)bh * DH + nst * 16 + lr) * FN_PAD + j0 + kk * 32 + lg * 8;
                bf16x8 vf = *(const bf16x8*)vp;
                oacc[nst] = __builtin_amdgcn_mfma_f32_16x16x32_bf16(pa, vf, oacc[nst], 0, 0, 0);
            }
        }
    }

    // ---- normalize + store ----
    float inv[4];
#pragma unroll
    for (int r = 0; r < 4; ++r) inv[r] = 1.0f / lsum[r];
#pragma unroll
    for (int nst = 0; nst < 4; ++nst)
#pragma unroll
        for (int r = 0; r < 4; ++r) {
            int row = q0 + lg * 4 + r;
            if (row < NL)
                o[((long)b * NL + row) * INNER + h * 64 + nst * 16 + lr] = oacc[nst][r] * inv[r];
        }
}

// ------------------------------- host side ----------------------------------
static void launch_gemm(const float* A, const float* W, float* C, float* C2,
                        const float* g, const float* bv,
                        int M, int N, int K,
                        int rpb, long long cbs, int roff, int ldc,
                        float scale, int mode, hipStream_t s)
{
    dim3 grid((M + 63) / 64, N / 64);
    gemm_kernel<<<grid, 256, 0, s>>>(A, W, C, C2, g, bv, M, N, K, rpb, cbs, roff, ldc, scale, mode);
}

extern "C" void kernel_launch(void* const* d_in, const int* in_sizes, int n_in,
                              void* d_out, int out_size, void* d_ws, size_t ws_size,
                              hipStream_t stream)
{
    const float* x        = (const float*)d_in[0];
    const int*   split    = (const int*)d_in[1];
    const float* latents  = (const float*)d_in[2];
    const float* sp_emb   = (const float*)d_in[3];
    const float* fr_emb   = (const float*)d_in[4];
    const float* nm_g     = (const float*)d_in[5];
    const float* nm_b     = (const float*)d_in[6];
    const float* nl_g     = (const float*)d_in[7];
    const float* nl_b     = (const float*)d_in[8];
    const float* wq       = (const float*)d_in[9];
    const float* wkv      = (const float*)d_in[10];
    const float* wo       = (const float*)d_in[11];
    const float* ffn_g    = (const float*)d_in[12];
    const float* ffn_b    = (const float*)d_in[13];
    const float* ffw1     = (const float*)d_in[14];
    const float* ffw2     = (const float*)d_in[15];
    const float* final_g  = (const float*)d_in[16];
    const float* final_b  = (const float*)d_in[17];
    float* out = (float*)d_out;

    // workspace layout
    float* ws = (float*)d_ws;
    const long XH = (long)B * F * D;            // 4,325,376 f
    const long LT = (long)B * NL * D;            // 1,476,608 f
    const long QS = (long)B * NL * INNER;        //   738,304 f
    const long H1 = (long)B * NL * 4 * D;        // 5,906,432 f
    float* xhat = ws;
    float* lat  = xhat + XH;
    float* latn = lat + LT;
    float* ob   = latn + LT;
    float* h1   = ob + QS;
    unsigned short* qb_u = (unsigned short*)(h1 + H1);           // B*NL_PAD*INNER
    unsigned short* kb_u = qb_u + (long)B * NL_PAD * INNER;      // B*FN_PAD*INNER
    unsigned short* vt_u = kb_u + (long)B * FN_PAD * INNER;      // B*H*DH*FN_PAD

    emb_ln_kernel<<<B * F, 256, 0, stream>>>(x, sp_emb, fr_emb, xhat);
    lat_init_kernel<<<B * NL, 256, 0, stream>>>(latents, lat);

    const int MLAT = B * NL;   // 1442
    const int MX   = B * F;    // 4224

    for (int l = 0; l < DEPTH; ++l) {
        const float* wq_l   = wq   + (long)l * D * INNER;
        const float* wkv_l  = wkv  + (long)l * D * 2 * INNER;
        const float* wo_l   = wo   + (long)l * INNER * D;
        const float* ffw1_l = ffw1 + (long)l * D * 4 * D;
        const float* ffw2_l = ffw2 + (long)l * 4 * D * D;

        rownorm_kernel<<<MLAT, 256, 0, stream>>>(lat, latn);

        // q = (latn*nl_g+nl_b) @ wq * scale   -> bf16 [B][NL_PAD][INNER]
        launch_gemm(latn, wq_l, (float*)qb_u, nullptr, nl_g + l * D, nl_b + l * D,
                    MLAT, INNER, D, NL, (long long)NL_PAD * INNER, 0, INNER,
                    0.125f, MODE_BF16, stream);

        // kv (x part): K bf16 rows [0,F), V transposed
        launch_gemm(xhat, wkv_l, (float*)kb_u, (float*)vt_u, nm_g + l * D, nm_b + l * D,
                    MX, 2 * INNER, D, F, 0, 0, 0, 1.0f, MODE_KV, stream);
        // kv (latent part): rows [F, FN)
        launch_gemm(latn, wkv_l, (float*)kb_u, (float*)vt_u, nl_g + l * D, nl_b + l * D,
                    MLAT, 2 * INNER, D, NL, 0, F, 0, 1.0f, MODE_KV, stream);

        // fused MFMA attention
        attn_mfma_kernel<<<dim3((NL + 63) / 64, B * H), 256, 0, stream>>>(
            qb_u, kb_u, vt_u, split, ob);

        // lat += o @ wo
        launch_gemm(ob, wo_l, lat, nullptr, nullptr, nullptr,
                    MLAT, D, INNER, MLAT, 0, 0, D, 1.0f, MODE_RES, stream);

        // FFN
        rownorm_kernel<<<MLAT, 256, 0, stream>>>(lat, latn);
        launch_gemm(latn, ffw1_l, h1, nullptr, ffn_g + l * D, ffn_b + l * D,
                    MLAT, 4 * D, D, MLAT, 0, 0, 4 * D, 1.0f, MODE_GELU, stream);
        launch_gemm(h1, ffw2_l, lat, nullptr, nullptr, nullptr,
                    MLAT, D, 4 * D, MLAT, 0, 0, D, 1.0f, MODE_RES, stream);
    }

    final_ln_kernel<<<MLAT, 256, 0, stream>>>(lat, final_g, final_b, out);
}